// Round 1
// baseline (209.908 us; speedup 1.0000x reference)
//
#include <hip/hip_runtime.h>

// BD-format field offsets (D = 512)
#define MARK_AX      0
#define OP_SHL       39
#define OP_SHR       40
#define ALU_LO       64
#define ALU_HI       80
#define AX_CARRY_LO  96
#define OUTPUT_LO    128
#define OUTPUT_HI    144

constexpr int D = 512;

__global__ __launch_bounds__(256) void shift_ffn_kernel(
    const float* __restrict__ x, float* __restrict__ out, int ntok)
{
    const int lane = threadIdx.x & 63;
    const int wid  = (blockIdx.x * blockDim.x + threadIdx.x) >> 6;
    const int nw   = (gridDim.x * blockDim.x) >> 6;
    const int e0   = 4 * lane;            // first element this lane covers (A-half)

    for (int tok = wid; tok < ntok; tok += nw) {
        const float* xt = x   + (size_t)tok * D;
        float*       ot = out + (size_t)tok * D;

        // Two fully-coalesced float4 loads: lane l -> elems [4l,4l+4) and [256+4l, ...)
        float4 a = *reinterpret_cast<const float4*>(xt + e0);
        float4 b = *reinterpret_cast<const float4*>(xt + 256 + e0);

        // Build per-lane control mask:
        //   bits  0..15 : ALU_LO one-hot   (elems 64..79)
        //   bits 16..31 : ALU_HI one-hot   (elems 80..95)
        //   bits 32..47 : shift-amt one-hot(elems 96..111)
        //   bit  48     : mark  (elem 0)
        //   bit  49     : OP_SHL (elem 39)
        //   bit  50     : OP_SHR (elem 40)
        unsigned long long m = 0ull;
        if (lane < 28) {   // all control elems are < 112
            const float av[4] = {a.x, a.y, a.z, a.w};
            #pragma unroll
            for (int j = 0; j < 4; ++j) {
                const int e = e0 + j;
                if (av[j] > 0.5f) {
                    if (e == MARK_AX)                              m |= 1ull << 48;
                    else if (e == OP_SHL)                          m |= 1ull << 49;
                    else if (e == OP_SHR)                          m |= 1ull << 50;
                    else if (e >= ALU_LO      && e < ALU_LO + 16)  m |= 1ull << (e - ALU_LO);
                    else if (e >= ALU_HI      && e < ALU_HI + 16)  m |= 1ull << (e - ALU_HI + 16);
                    else if (e >= AX_CARRY_LO && e < AX_CARRY_LO+16) m |= 1ull << (e - AX_CARRY_LO + 32);
                }
            }
        }

        // Wave-wide OR-reduce (butterfly over 64 lanes)
        #pragma unroll
        for (int s = 1; s < 64; s <<= 1)
            m |= __shfl_xor(m, s, 64);

        // Decode token state (identical on all lanes)
        const unsigned lo16 = (unsigned)( m        & 0xFFFFu);
        const unsigned hi16 = (unsigned)((m >> 16) & 0xFFFFu);
        const unsigned sa16 = (unsigned)((m >> 32) & 0xFFFFu);
        const int lo = lo16 ? (__ffs(lo16) - 1) : 0;   // first k with >0.5, 0 if none (= argmax)
        const int hi = hi16 ? (__ffs(hi16) - 1) : 0;
        const int sa = sa16 ? (__ffs(sa16) - 1) : 0;

        const int  val     = lo + 16 * hi;                 // 8-bit operand
        const bool mark    = (m >> 48) & 1ull;
        const bool is_shl  = (m >> 49) & 1ull;
        const bool is_shr  = (((m >> 50) & 1ull) != 0) && !is_shl;  // elif priority
        const bool act_shl = mark && is_shl;
        const bool act_shr = mark && is_shr;
        const bool active  = act_shl || act_shr;

        int res = 0;
        if (act_shl)      res = (val << sa) & 0xFF;
        else if (act_shr) res = val >> sa;                 // logical, val <= 255 so OK
        // res already in [0,255]

        const int tlo = OUTPUT_LO + (res & 15);   // in [128,144)
        const int thi = OUTPUT_HI + (res >> 4);   // in [144,160)

        // Apply scatter adds (targets always in the A-half: elems < 256)
        if (active) {
            float* ap = &a.x;
            #pragma unroll
            for (int j = 0; j < 4; ++j) {
                const int e = e0 + j;
                float add = 0.0f;
                if (e == tlo) add += 2.0f;
                if (e == thi) add += 2.0f;
                ap[j] += add;
            }
        }

        *reinterpret_cast<float4*>(ot + e0)       = a;
        *reinterpret_cast<float4*>(ot + 256 + e0) = b;
    }
}

extern "C" void kernel_launch(void* const* d_in, const int* in_sizes, int n_in,
                              void* d_out, int out_size, void* d_ws, size_t ws_size,
                              hipStream_t stream)
{
    const float* x = (const float*)d_in[0];
    float* out = (float*)d_out;
    const int ntok = in_sizes[0] / D;   // 8 * 32768 = 262144

    const int block = 256;              // 4 waves/block
    const int grid  = 2048;             // 8192 waves, grid-stride over tokens
    shift_ffn_kernel<<<grid, block, 0, stream>>>(x, out, ntok);
}

// Round 2
// 188.233 us; speedup vs baseline: 1.1152x; 1.1152x over previous
//
#include <hip/hip_runtime.h>

// BD-format field offsets (D = 512)
#define MARK_AX      0
#define OP_SHL       39   // elem 39 = 4*9 + 3  -> ballot[3] bit 9
#define OP_SHR       40   // elem 40 = 4*10 + 0 -> ballot[0] bit 10
#define ALU_LO       64   // lanes 16..19
#define ALU_HI       80   // lanes 20..23
#define AX_CARRY_LO  96   // lanes 24..27
#define OUTPUT_LO    128
#define OUTPUT_HI    144

constexpr int D = 512;

typedef float f32x4 __attribute__((ext_vector_type(4)));

// First hot index (0 if none) of the 16-wide field whose elements live in
// lanes [lane0, lane0+4). elem = 4*l + j  ->  field idx k = 4*(l-lane0) + j.
__device__ __forceinline__ int first_hot(const unsigned long long b[4], int lane0) {
    int best = 999;
    #pragma unroll
    for (int j = 0; j < 4; ++j) {
        unsigned nib = (unsigned)(b[j] >> lane0) & 0xFu;
        int cand = nib ? (4 * (__ffs(nib) - 1) + j) : 999;
        best = min(best, cand);
    }
    return (best >= 16) ? 0 : best;   // argmax-of-bool: 0 when no bit set
}

__device__ __forceinline__ void decode(const unsigned long long b[4],
                                       int& tlo, int& thi, float& amp) {
    const bool mark = (b[0] >> 0) & 1ull;    // elem 0
    const bool shl  = (b[3] >> 9) & 1ull;    // elem 39
    const bool shr  = (b[0] >> 10) & 1ull;   // elem 40

    const int lo = first_hot(b, 16);         // elems 64..79
    const int hi = first_hot(b, 20);         // elems 80..95
    const int sa = first_hot(b, 24);         // elems 96..111

    const int  val     = lo + 16 * hi;
    const bool act_shl = mark && shl;
    const bool act_shr = mark && shr && !shl;  // elif priority

    const int res = act_shl ? ((val << sa) & 0xFF)
                  : (act_shr ? (val >> sa) : 0);

    tlo = OUTPUT_LO + (res & 15);
    thi = OUTPUT_HI + (res >> 4);
    amp = (act_shl || act_shr) ? 2.0f : 0.0f;
}

__global__ __launch_bounds__(256) void shift_ffn_kernel(
    const float* __restrict__ x, float* __restrict__ out, int ntok)
{
    const int lane = threadIdx.x & 63;
    const int wid  = (blockIdx.x * blockDim.x + threadIdx.x) >> 6;
    const int nw   = (gridDim.x * blockDim.x) >> 6;
    const int e0   = 4 * lane;
    const int npair = ntok >> 1;              // ntok is even (8*32768)

    for (int p = wid; p < npair; p += nw) {
        const float* xt0 = x   + (size_t)(2 * p) * D;
        float*       ot0 = out + (size_t)(2 * p) * D;

        // Issue all 4 token loads up front (2 tokens, 2 halves each)
        f32x4 a0 = __builtin_nontemporal_load((const f32x4*)(xt0 + e0));
        f32x4 c0 = __builtin_nontemporal_load((const f32x4*)(xt0 + 256 + e0));
        f32x4 a1 = __builtin_nontemporal_load((const f32x4*)(xt0 + D + e0));
        f32x4 c1 = __builtin_nontemporal_load((const f32x4*)(xt0 + D + 256 + e0));

        // Ballot-based control gather: b[j] bit l == (elem 4l+j > 0.5)
        unsigned long long b0[4], b1[4];
        #pragma unroll
        for (int j = 0; j < 4; ++j) b0[j] = __ballot(a0[j] > 0.5f);
        #pragma unroll
        for (int j = 0; j < 4; ++j) b1[j] = __ballot(a1[j] > 0.5f);

        int tlo0, thi0, tlo1, thi1; float amp0, amp1;
        decode(b0, tlo0, thi0, amp0);
        decode(b1, tlo1, thi1, amp1);

        #pragma unroll
        for (int j = 0; j < 4; ++j) {
            const int e = e0 + j;
            a0[j] += ((e == tlo0) ? amp0 : 0.0f) + ((e == thi0) ? amp0 : 0.0f);
            a1[j] += ((e == tlo1) ? amp1 : 0.0f) + ((e == thi1) ? amp1 : 0.0f);
        }

        __builtin_nontemporal_store(a0, (f32x4*)(ot0 + e0));
        __builtin_nontemporal_store(c0, (f32x4*)(ot0 + 256 + e0));
        __builtin_nontemporal_store(a1, (f32x4*)(ot0 + D + e0));
        __builtin_nontemporal_store(c1, (f32x4*)(ot0 + D + 256 + e0));
    }
}

extern "C" void kernel_launch(void* const* d_in, const int* in_sizes, int n_in,
                              void* d_out, int out_size, void* d_ws, size_t ws_size,
                              hipStream_t stream)
{
    const float* x = (const float*)d_in[0];
    float* out = (float*)d_out;
    const int ntok = in_sizes[0] / D;   // 262144

    const int block = 256;              // 4 waves/block
    const int grid  = 2048;             // 8192 waves; 16 token-pairs per wave
    shift_ffn_kernel<<<grid, block, 0, stream>>>(x, out, ntok);
}